// Round 1
// baseline (358.501 us; speedup 1.0000x reference)
//
#include <hip/hip_runtime.h>
#include <stdint.h>

// ---------------------------------------------------------------------------
// MultiHeadedAttention: B=8, N=1024, E=512, H=8, D_K=64
// out = ((softmax(mask(QK^T/8)) V) concat-heads) @ Wo^T + bo
// bf16 MFMA pipeline (tolerance is 2% of max|ref| => bf16-class)
// ---------------------------------------------------------------------------

typedef __attribute__((ext_vector_type(8))) short short8;
typedef __attribute__((ext_vector_type(4))) float floatx4;

#define MFMA16(a, b, c) __builtin_amdgcn_mfma_f32_16x16x32_bf16((a), (b), (c), 0, 0, 0)

static __device__ __forceinline__ unsigned short f2bf(float f) {
  union { float f; unsigned u; } v; v.f = f;
  unsigned r = v.u + 0x7fffu + ((v.u >> 16) & 1u);   // RNE
  return (unsigned short)(r >> 16);
}
static __device__ __forceinline__ float bf2f(unsigned short h) {
  union { unsigned u; float f; } v; v.u = ((unsigned)h) << 16;
  return v.f;
}
// XOR swizzle on P columns: spreads the 4 C-layout quads (rows 4 apart) and
// 4 regs (rows 1 apart) across LDS banks. Bijective within each 32-col block.
static __device__ __forceinline__ int pcol(int row, int col) {
  return col ^ (((row >> 2) & 3) << 4) ^ ((row & 3) << 3);
}

// ---------------- cast fp32 -> bf16 (vectorized) ----------------
__global__ void cast_kernel(const float* __restrict__ src, unsigned short* __restrict__ dst, int n4) {
  int i = blockIdx.x * blockDim.x + threadIdx.x;
  if (i >= n4) return;
  float4 v = ((const float4*)src)[i];
  ushort4 o;
  o.x = f2bf(v.x); o.y = f2bf(v.y); o.z = f2bf(v.z); o.w = f2bf(v.w);
  ((ushort4*)dst)[i] = o;
}

// ---------------- dist+mask -> per-(b,i,j) code byte ----------------
// allowed(h) <=> h >= code.  DIST_BAR ascending => dmask monotone in h.
// code = 9 if mask==0 (never); 0 if i==0||j==0; else #thresholds <= dist.
__global__ void codes_kernel(const float* __restrict__ dist, const int* __restrict__ mask,
                             unsigned char* __restrict__ codes) {
  int t = blockIdx.x * blockDim.x + threadIdx.x;   // over B*N*N/4
  int flat = t << 2;
  int rem = flat & ((1 << 20) - 1);
  int i = rem >> 10;
  int j0 = rem & 1023;
  float4 d4 = ((const float4*)dist)[t];
  int4 m4 = ((const int4*)mask)[t];
  float dv[4] = {d4.x, d4.y, d4.z, d4.w};
  int mv[4] = {m4.x, m4.y, m4.z, m4.w};
  unsigned char cv[4];
#pragma unroll
  for (int u = 0; u < 4; u++) {
    float d = dv[u];
    int hmin = (d >= 0.2f) + (d >= 0.3f) + (d >= 0.4f) + (d >= 0.5f) +
               (d >= 0.6f) + (d >= 0.7f) + (d >= 0.8f) + (d >= 0.9f);
    unsigned char cc = (unsigned char)hmin;
    if (i == 0 || (j0 + u) == 0) cc = 0;
    if (mv[u] == 0) cc = 9;
    cv[u] = cc;
  }
  uchar4 o; o.x = cv[0]; o.y = cv[1]; o.z = cv[2]; o.w = cv[3];
  ((uchar4*)codes)[t] = o;
}

// ---------------- GEMM: C[m][n] = sum_k A[m][k] * W[n][k] + bias[n] ----------------
// M=8192, N=512, K=512.  128x128 tile, 4 waves (each 64x64 = 4x4 MFMA tiles).
// mode 0/1: write bf16 to head layout [b][h][n][d]
// mode 2:   write bf16 transposed   [b][h][d][n]   (V for PV B-fragments)
// mode 3:   write fp32 to d_out [m][n]
#define LDK 40   // padded LDS row stride (elems); 80B keeps 16B alignment, breaks 64B bank stride
__global__ __launch_bounds__(256) void gemm_bt(const unsigned short* __restrict__ A,
                                               const unsigned short* __restrict__ Bw,
                                               const float* __restrict__ bias,
                                               void* __restrict__ Cout, int mode) {
  __shared__ short As[128 * LDK];
  __shared__ short Bs[128 * LDK];
  const int tid = threadIdx.x;
  const int lane = tid & 63;
  const int wave = tid >> 6;
  const int c = lane & 15;
  const int q = lane >> 4;
  const int m0 = blockIdx.x * 128;
  const int n0 = blockIdx.y * 128;
  const int wr = (wave >> 1) * 64;
  const int wc = (wave & 1) * 64;

  floatx4 acc[4][4];
#pragma unroll
  for (int i = 0; i < 4; i++)
#pragma unroll
    for (int j = 0; j < 4; j++) acc[i][j] = (floatx4)(0.0f);

  for (int k0 = 0; k0 < 512; k0 += 32) {
    __syncthreads();
#pragma unroll
    for (int it = 0; it < 2; it++) {
      int id = it * 256 + tid;          // 0..511 : 128 rows x 4 chunks of 8 bf16
      int row = id >> 2, kc = id & 3;
      short8 av = *(const short8*)(A + (size_t)(m0 + row) * 512 + k0 + kc * 8);
      short8 bv = *(const short8*)(Bw + (size_t)(n0 + row) * 512 + k0 + kc * 8);
      *(short8*)(&As[row * LDK + kc * 8]) = av;
      *(short8*)(&Bs[row * LDK + kc * 8]) = bv;
    }
    __syncthreads();
    short8 af[4], bfv[4];
#pragma unroll
    for (int i = 0; i < 4; i++)
      af[i] = *(const short8*)(&As[(wr + i * 16 + c) * LDK + q * 8]);
#pragma unroll
    for (int j = 0; j < 4; j++)
      bfv[j] = *(const short8*)(&Bs[(wc + j * 16 + c) * LDK + q * 8]);
#pragma unroll
    for (int i = 0; i < 4; i++)
#pragma unroll
      for (int j = 0; j < 4; j++)
        acc[i][j] = MFMA16(af[i], bfv[j], acc[i][j]);
  }

  // Epilogue.  C/D layout: col = lane&15, row = (lane>>4)*4 + reg  [m89-verified]
#pragma unroll
  for (int i = 0; i < 4; i++) {
    int gm0 = m0 + wr + i * 16 + q * 4;
#pragma unroll
    for (int j = 0; j < 4; j++) {
      int gn = n0 + wc + j * 16 + c;
      float bb = bias[gn];
#pragma unroll
      for (int r = 0; r < 4; r++) {
        float val = acc[i][j][r] + bb;
        int m = gm0 + r;
        if (mode == 3) {
          ((float*)Cout)[(size_t)m * 512 + gn] = val;
        } else {
          int b = m >> 10, n = m & 1023;
          int h = gn >> 6, d = gn & 63;
          unsigned short* O = (unsigned short*)Cout;
          if (mode == 2)
            O[(((size_t)(b * 8 + h) * 64 + d) << 10) + n] = f2bf(val);   // [bh][d][n]
          else
            O[((((size_t)(b * 8 + h)) << 10) + n) * 64 + d] = f2bf(val); // [bh][n][d]
        }
      }
    }
  }
}

// ---------------- fused masked-softmax attention ----------------
// One WG per (b,h, 32-row q tile).  No max subtraction: scores ~N(0,1), safe.
// Phase 1: S = QK^T/8 -> e = allowed ? exp(s) : 0, store bf16 in LDS P[32][1024].
// Phase 2: per-wave row sums (shuffle), O = P@V via MFMA, normalize in epilogue.
__global__ __launch_bounds__(256) void attn_kernel(const unsigned short* __restrict__ Qh,
                                                   const unsigned short* __restrict__ Kh,
                                                   const unsigned short* __restrict__ Vt,
                                                   const unsigned char* __restrict__ codes,
                                                   unsigned short* __restrict__ AO) {
  __shared__ unsigned short P[32 * 1024];   // 64 KB
  const int tid = threadIdx.x;
  const int lane = tid & 63;
  const int wave = tid >> 6;
  const int c = lane & 15;
  const int q = lane >> 4;
  const int qt = blockIdx.x;        // 0..31
  const int bh = blockIdx.y;        // 0..63
  const int b = bh >> 3;
  const int h = bh & 7;
  const size_t base = (size_t)bh << 16;     // bh * 1024 * 64

  // Q fragments, loaded once (rows qt*32 + ri*16 + c; k chunks kk*32 + q*8)
  short8 aq[2][2];
#pragma unroll
  for (int ri = 0; ri < 2; ri++)
#pragma unroll
    for (int kk = 0; kk < 2; kk++)
      aq[ri][kk] = *(const short8*)(Qh + base + (size_t)(qt * 32 + ri * 16 + c) * 64 + kk * 32 + q * 8);

  const unsigned char* cb = codes + ((size_t)b << 20);

  // ---- Phase 1: scores -> exp -> P (each wave owns a 32-col stripe per kt) ----
  for (int kt = 0; kt < 8; kt++) {
    int col0 = kt * 128 + wave * 32;
    floatx4 s[2][2];
#pragma unroll
    for (int ri = 0; ri < 2; ri++)
#pragma unroll
      for (int ci = 0; ci < 2; ci++) s[ri][ci] = (floatx4)(0.0f);
#pragma unroll
    for (int ci = 0; ci < 2; ci++) {
#pragma unroll
      for (int kk = 0; kk < 2; kk++) {
        short8 bk = *(const short8*)(Kh + base + (size_t)(col0 + ci * 16 + c) * 64 + kk * 32 + q * 8);
        s[0][ci] = MFMA16(aq[0][kk], bk, s[0][ci]);
        s[1][ci] = MFMA16(aq[1][kk], bk, s[1][ci]);
      }
    }
#pragma unroll
    for (int ri = 0; ri < 2; ri++) {
      int rowl = ri * 16 + q * 4;
#pragma unroll
      for (int ci = 0; ci < 2; ci++) {
        int col = col0 + ci * 16 + c;
#pragma unroll
        for (int r = 0; r < 4; r++) {
          int row = rowl + r;
          int ig = qt * 32 + row;
          unsigned char code = cb[((size_t)ig << 10) + col];
          float e = (h >= (int)code) ? __expf(s[ri][ci][r] * 0.125f) : 0.0f;
          P[row * 1024 + pcol(row, col)] = f2bf(e);
        }
      }
    }
  }
  __syncthreads();

  // ---- row sums (per wave, rows ri*16 + 0..15), then PV ----
  const int ri = wave >> 1;
  const int ci0 = (wave & 1) * 2;
  float rsum = 0.0f;
  {
    int row = ri * 16 + c;
    int rbase = row * 1024;
#pragma unroll 4
    for (int g = 0; g < 32; g++) {                 // lane sums cols q*256 .. q*256+255
      int col = q * 256 + g * 8;
      short8 pv = *(const short8*)(&P[rbase + pcol(row, col)]);
#pragma unroll
      for (int u = 0; u < 8; u++) rsum += bf2f((unsigned short)pv[u]);
    }
  }
  rsum += __shfl_xor(rsum, 16);
  rsum += __shfl_xor(rsum, 32);                    // lanes sharing c hold sum of row ri*16+c
  float inv[4];
#pragma unroll
  for (int r = 0; r < 4; r++) inv[r] = 1.0f / __shfl(rsum, q * 4 + r);

  floatx4 o0 = (floatx4)(0.0f), o1 = (floatx4)(0.0f);
  const unsigned short* Vb = Vt + base;
  {
    int row = ri * 16 + c;
    int rbase = row * 1024;
    for (int st = 0; st < 32; st++) {
      short8 ap = *(const short8*)(&P[rbase + pcol(row, st * 32 + q * 8)]);
      short8 bv0 = *(const short8*)(Vb + (size_t)(ci0 * 16 + c) * 1024 + st * 32 + q * 8);
      short8 bv1 = *(const short8*)(Vb + (size_t)((ci0 + 1) * 16 + c) * 1024 + st * 32 + q * 8);
      o0 = MFMA16(ap, bv0, o0);
      o1 = MFMA16(ap, bv1, o1);
    }
  }
  // epilogue: AO[b][n][h*64+d]  (concat-heads layout for the output GEMM)
  int hbase = h * 64;
#pragma unroll
  for (int r = 0; r < 4; r++) {
    int il = ri * 16 + q * 4 + r;
    int ig = qt * 32 + il;
    size_t obase = ((size_t)(b * 1024 + ig)) * 512 + hbase;
    AO[obase + ci0 * 16 + c] = f2bf(o0[r] * inv[r]);
    AO[obase + (ci0 + 1) * 16 + c] = f2bf(o1[r] * inv[r]);
  }
}

// ---------------- launcher ----------------
extern "C" void kernel_launch(void* const* d_in, const int* in_sizes, int n_in,
                              void* d_out, int out_size, void* d_ws, size_t ws_size,
                              hipStream_t stream) {
  const float* query = (const float*)d_in[0];
  const float* key_  = (const float*)d_in[1];
  const float* value = (const float*)d_in[2];
  const float* dist  = (const float*)d_in[3];
  const int*   mask  = (const int*)d_in[4];
  const float* Wq = (const float*)d_in[5];
  const float* bq = (const float*)d_in[6];
  const float* Wk = (const float*)d_in[7];
  const float* bk = (const float*)d_in[8];
  const float* Wv = (const float*)d_in[9];
  const float* bv = (const float*)d_in[10];
  const float* Wo = (const float*)d_in[11];
  const float* bo = (const float*)d_in[12];

  char* ws = (char*)d_ws;
  size_t off = 0;
  auto alloc = [&](size_t bytes) -> char* {
    char* p = ws + off;
    off += (bytes + 255) & ~(size_t)255;
    return p;
  };
  const size_t NQKV = 8192ull * 512;         // 4,194,304 elems
  unsigned short* qb  = (unsigned short*)alloc(NQKV * 2);
  unsigned short* kb  = (unsigned short*)alloc(NQKV * 2);
  unsigned short* vb  = (unsigned short*)alloc(NQKV * 2);
  unsigned short* wq16 = (unsigned short*)alloc(512ull * 512 * 2);
  unsigned short* wk16 = (unsigned short*)alloc(512ull * 512 * 2);
  unsigned short* wv16 = (unsigned short*)alloc(512ull * 512 * 2);
  unsigned short* wo16 = (unsigned short*)alloc(512ull * 512 * 2);
  unsigned short* Qh = (unsigned short*)alloc(NQKV * 2);
  unsigned short* Kh = (unsigned short*)alloc(NQKV * 2);
  unsigned short* Vt = (unsigned short*)alloc(NQKV * 2);
  unsigned short* AO = (unsigned short*)alloc(NQKV * 2);
  unsigned char*  codes = (unsigned char*)alloc(8ull * 1024 * 1024);

  cast_kernel<<<4096, 256, 0, stream>>>(query, qb, (int)(NQKV / 4));
  cast_kernel<<<4096, 256, 0, stream>>>(key_,  kb, (int)(NQKV / 4));
  cast_kernel<<<4096, 256, 0, stream>>>(value, vb, (int)(NQKV / 4));
  cast_kernel<<<256, 256, 0, stream>>>(Wq, wq16, 65536);
  cast_kernel<<<256, 256, 0, stream>>>(Wk, wk16, 65536);
  cast_kernel<<<256, 256, 0, stream>>>(Wv, wv16, 65536);
  cast_kernel<<<256, 256, 0, stream>>>(Wo, wo16, 65536);
  codes_kernel<<<8192, 256, 0, stream>>>(dist, mask, codes);

  dim3 ggrid(64, 4);
  gemm_bt<<<ggrid, 256, 0, stream>>>(qb, wq16, bq, Qh, 0);
  gemm_bt<<<ggrid, 256, 0, stream>>>(kb, wk16, bk, Kh, 1);
  gemm_bt<<<ggrid, 256, 0, stream>>>(vb, wv16, bv, Vt, 2);

  attn_kernel<<<dim3(32, 64), 256, 0, stream>>>(Qh, Kh, Vt, codes, AO);

  gemm_bt<<<ggrid, 256, 0, stream>>>(AO, wo16, bo, d_out, 3);
}

// Round 2
// 305.520 us; speedup vs baseline: 1.1734x; 1.1734x over previous
//
#include <hip/hip_runtime.h>
#include <stdint.h>

// ---------------------------------------------------------------------------
// MultiHeadedAttention: B=8, N=1024, E=512, H=8, D_K=64
// bf16 MFMA pipeline, flash-style attention, global_load_lds GEMM staging.
// ---------------------------------------------------------------------------

typedef __attribute__((ext_vector_type(8))) short short8;
typedef __attribute__((ext_vector_type(4))) float floatx4;

#define MFMA16(a, b, c) __builtin_amdgcn_mfma_f32_16x16x32_bf16((a), (b), (c), 0, 0, 0)

static __device__ __forceinline__ unsigned short f2bf(float f) {
  union { float f; unsigned u; } v; v.f = f;
  unsigned r = v.u + 0x7fffu + ((v.u >> 16) & 1u);   // RNE
  return (unsigned short)(r >> 16);
}

// async global->LDS 16B/lane. LDS dest is wave-uniform base + lane*16 (m104).
static __device__ __forceinline__ void gload_lds16(const void* g, void* l) {
  __builtin_amdgcn_global_load_lds((const __attribute__((address_space(1))) unsigned int*)g,
                                   (__attribute__((address_space(3))) unsigned int*)l,
                                   16, 0, 0);
}
// chunk swizzle for unpadded 32-elem-wide bf16 LDS tiles: global chunk for
// (row, LDS-chunk ch) is ch ^ x(row); gives 2-way max on b128 frag reads (free).
static __device__ __forceinline__ int xsw(int row) { return (row & 3) ^ ((row >> 2) & 3); }

// ---------------- weight cast fp32 -> bf16 (all 4 at once) ----------------
__global__ void wcast_kernel(const float* __restrict__ Wq, const float* __restrict__ Wk,
                             const float* __restrict__ Wv, const float* __restrict__ Wo,
                             unsigned short* __restrict__ o0, unsigned short* __restrict__ o1,
                             unsigned short* __restrict__ o2, unsigned short* __restrict__ o3) {
  int i = blockIdx.x * blockDim.x + threadIdx.x;   // 0..262143
  int w = i >> 16, loc = i & 65535;
  const float* s = (w == 0) ? Wq : (w == 1) ? Wk : (w == 2) ? Wv : Wo;
  unsigned short* d = (w == 0) ? o0 : (w == 1) ? o1 : (w == 2) ? o2 : o3;
  float4 v = ((const float4*)s)[loc];
  ushort4 o;
  o.x = f2bf(v.x); o.y = f2bf(v.y); o.z = f2bf(v.z); o.w = f2bf(v.w);
  ((ushort4*)d)[loc] = o;
}

// ---------------- dist+mask -> per-(b,i,j) code byte ----------------
// allowed(h) <=> h >= code (DIST_BAR ascending). 0 on row/col 0; 9 if mask==0.
__global__ void codes_kernel(const float* __restrict__ dist, const int* __restrict__ mask,
                             unsigned char* __restrict__ codes) {
  int t = blockIdx.x * blockDim.x + threadIdx.x;   // over B*N*N/4
  int flat = t << 2;
  int rem = flat & ((1 << 20) - 1);
  int i = rem >> 10;
  int j0 = rem & 1023;
  float4 d4 = ((const float4*)dist)[t];
  int4 m4 = ((const int4*)mask)[t];
  float dv[4] = {d4.x, d4.y, d4.z, d4.w};
  int mv[4] = {m4.x, m4.y, m4.z, m4.w};
  unsigned char cv[4];
#pragma unroll
  for (int u = 0; u < 4; u++) {
    float d = dv[u];
    int hmin = (d >= 0.2f) + (d >= 0.3f) + (d >= 0.4f) + (d >= 0.5f) +
               (d >= 0.6f) + (d >= 0.7f) + (d >= 0.8f) + (d >= 0.9f);
    unsigned char cc = (unsigned char)hmin;
    if (i == 0 || (j0 + u) == 0) cc = 0;
    if (mv[u] == 0) cc = 9;
    cv[u] = cc;
  }
  uchar4 o; o.x = cv[0]; o.y = cv[1]; o.z = cv[2]; o.w = cv[3];
  ((uchar4*)codes)[t] = o;
}

// ---------------- fused QKV projection GEMM ----------------
// C[m][n] = sum_k A[m][k] * W[n][k] + bias[n];  M=8192, N=512, K=512.
// 64x128 tile, 4 waves (each 32x64). A is fp32 (cast fused into staging).
// z = 0/1: head layout [bh][n][d];  z = 2: transposed [bh][d][n].
__global__ __launch_bounds__(256) void qkv_gemm(
    const float* __restrict__ Aq, const float* __restrict__ Ak, const float* __restrict__ Av,
    const unsigned short* __restrict__ Wqp, const unsigned short* __restrict__ Wkp,
    const unsigned short* __restrict__ Wvp,
    const float* __restrict__ bq, const float* __restrict__ bk, const float* __restrict__ bv,
    unsigned short* __restrict__ Qh, unsigned short* __restrict__ Kh,
    unsigned short* __restrict__ Vt) {
  const int z = blockIdx.z;
  const float* A = (z == 0) ? Aq : (z == 1) ? Ak : Av;
  const unsigned short* W = (z == 0) ? Wqp : (z == 1) ? Wkp : Wvp;
  const float* bias = (z == 0) ? bq : (z == 1) ? bk : bv;
  unsigned short* O = (z == 0) ? Qh : (z == 1) ? Kh : Vt;

  __shared__ __align__(16) short As[64 * 40];    // padded, written by VALU (cast)
  __shared__ __align__(16) short Bs[128 * 32];   // unpadded, global_load_lds + swizzle
  const int tid = threadIdx.x;
  const int lane = tid & 63;
  const int wave = tid >> 6;
  const int c = lane & 15;
  const int q = lane >> 4;
  const int m0 = blockIdx.x * 64;
  const int n0 = blockIdx.y * 128;
  const int wr = (wave >> 1) * 32;
  const int wc = (wave & 1) * 64;

  floatx4 acc[2][4];
#pragma unroll
  for (int i = 0; i < 2; i++)
#pragma unroll
    for (int j = 0; j < 4; j++) acc[i][j] = (floatx4)(0.0f);

  const int arow = tid >> 2, ach = tid & 3;  // A: 64 rows x 4 chunks of 8 floats
  const float* Ab = A + (size_t)(m0 + arow) * 512 + ach * 8;

  for (int k0 = 0; k0 < 512; k0 += 32) {
    __syncthreads();   // previous iteration's fragment reads complete
    // B: async DMA, 2 x 16B per lane, chunk-swizzled on the global side
#pragma unroll
    for (int it = 0; it < 2; it++) {
      int slot = wave * 128 + it * 64 + lane;
      int brow = slot >> 2, bch = slot & 3;
      int g = bch ^ xsw(brow);
      gload_lds16(W + (size_t)(n0 + brow) * 512 + k0 + g * 8,
                  &Bs[(size_t)(wave * 128 + it * 64) * 8]);
    }
    // A: fp32 load + convert + LDS write
    float4 a0 = *(const float4*)(Ab + k0);
    float4 a1 = *(const float4*)(Ab + k0 + 4);
    short8 av;
    av[0] = (short)f2bf(a0.x); av[1] = (short)f2bf(a0.y);
    av[2] = (short)f2bf(a0.z); av[3] = (short)f2bf(a0.w);
    av[4] = (short)f2bf(a1.x); av[5] = (short)f2bf(a1.y);
    av[6] = (short)f2bf(a1.z); av[7] = (short)f2bf(a1.w);
    *(short8*)(&As[arow * 40 + ach * 8]) = av;
    __syncthreads();   // staging complete (barrier drains vmcnt)

    short8 af[2], bfv[4];
#pragma unroll
    for (int i = 0; i < 2; i++)
      af[i] = *(const short8*)(&As[(wr + i * 16 + c) * 40 + q * 8]);
#pragma unroll
    for (int j = 0; j < 4; j++) {
      int row = wc + j * 16 + c;
      bfv[j] = *(const short8*)(&Bs[row * 32 + (q ^ xsw(row)) * 8]);
    }
#pragma unroll
    for (int i = 0; i < 2; i++)
#pragma unroll
      for (int j = 0; j < 4; j++)
        acc[i][j] = MFMA16(af[i], bfv[j], acc[i][j]);
  }

  // Epilogue.  C/D: col = lane&15, row = (lane>>4)*4 + reg  [m89-verified]
#pragma unroll
  for (int i = 0; i < 2; i++) {
    int gm0 = m0 + wr + i * 16 + q * 4;
#pragma unroll
    for (int j = 0; j < 4; j++) {
      int gn = n0 + wc + j * 16 + c;
      float bb = bias[gn];
      int h = gn >> 6, d = gn & 63;
      if (z == 2) {
        int b = gm0 >> 10, n = gm0 & 1023;
        ushort4 pk;
#pragma unroll
        for (int r = 0; r < 4; r++) pk[r] = f2bf(acc[i][j][r] + bb);
        *(ushort4*)(&Vt[(((size_t)(b * 8 + h) * 64 + d) << 10) + n]) = pk;  // [bh][d][n]
      } else {
#pragma unroll
        for (int r = 0; r < 4; r++) {
          int m = gm0 + r;
          int b = m >> 10, n = m & 1023;
          O[((((size_t)(b * 8 + h)) << 10) + n) * 64 + d] = f2bf(acc[i][j][r] + bb);
        }
      }
    }
  }
}

// ---------------- output projection GEMM (bf16 A, fp32 out) ----------------
__global__ __launch_bounds__(256) void out_gemm(const unsigned short* __restrict__ A,
                                                const unsigned short* __restrict__ W,
                                                const float* __restrict__ bias,
                                                float* __restrict__ Out) {
  __shared__ __align__(16) short As[64 * 32];    // unpadded, DMA + swizzle
  __shared__ __align__(16) short Bs[128 * 32];
  const int tid = threadIdx.x;
  const int lane = tid & 63;
  const int wave = tid >> 6;
  const int c = lane & 15;
  const int q = lane >> 4;
  const int m0 = blockIdx.x * 64;
  const int n0 = blockIdx.y * 128;
  const int wr = (wave >> 1) * 32;
  const int wc = (wave & 1) * 64;

  floatx4 acc[2][4];
#pragma unroll
  for (int i = 0; i < 2; i++)
#pragma unroll
    for (int j = 0; j < 4; j++) acc[i][j] = (floatx4)(0.0f);

  for (int k0 = 0; k0 < 512; k0 += 32) {
    __syncthreads();
    {  // A: 64 rows x 4 chunks, one 16B DMA per lane
      int slot = wave * 64 + lane;
      int arow = slot >> 2, ach = slot & 3;
      int g = ach ^ xsw(arow);
      gload_lds16(A + (size_t)(m0 + arow) * 512 + k0 + g * 8, &As[(size_t)(wave * 64) * 8]);
    }
#pragma unroll
    for (int it = 0; it < 2; it++) {
      int slot = wave * 128 + it * 64 + lane;
      int brow = slot >> 2, bch = slot & 3;
      int g = bch ^ xsw(brow);
      gload_lds16(W + (size_t)(n0 + brow) * 512 + k0 + g * 8,
                  &Bs[(size_t)(wave * 128 + it * 64) * 8]);
    }
    __syncthreads();

    short8 af[2], bfv[4];
#pragma unroll
    for (int i = 0; i < 2; i++) {
      int row = wr + i * 16 + c;
      af[i] = *(const short8*)(&As[row * 32 + (q ^ xsw(row)) * 8]);
    }
#pragma unroll
    for (int j = 0; j < 4; j++) {
      int row = wc + j * 16 + c;
      bfv[j] = *(const short8*)(&Bs[row * 32 + (q ^ xsw(row)) * 8]);
    }
#pragma unroll
    for (int i = 0; i < 2; i++)
#pragma unroll
      for (int j = 0; j < 4; j++)
        acc[i][j] = MFMA16(af[i], bfv[j], acc[i][j]);
  }

#pragma unroll
  for (int i = 0; i < 2; i++) {
    int gm0 = m0 + wr + i * 16 + q * 4;
#pragma unroll
    for (int j = 0; j < 4; j++) {
      int gn = n0 + wc + j * 16 + c;
      float bb = bias[gn];
#pragma unroll
      for (int r = 0; r < 4; r++)
        Out[(size_t)(gm0 + r) * 512 + gn] = acc[i][j][r] + bb;
    }
  }
}

// ---------------- flash-style masked-softmax attention ----------------
// One WG per (b,h, 32-row q tile). Per 128-col K tile: S = QK^T -> exp -> P
// tile in LDS (C->A layout transform) -> PV accumulate. Row sums accumulate
// in registers from the exp epilogue; normalize at the end. No max
// subtraction (scores ~N(0,1), exp-safe; matches round-1 verified math).
__global__ __launch_bounds__(256) void attn_kernel(const unsigned short* __restrict__ Qh,
                                                   const unsigned short* __restrict__ Kh,
                                                   const unsigned short* __restrict__ Vt,
                                                   const unsigned char* __restrict__ codes,
                                                   unsigned short* __restrict__ AO) {
  __shared__ __align__(16) unsigned short P[32 * 136];   // 8.5 KB, stride 136 (2-way max)
  __shared__ __align__(16) unsigned char Ct[32 * 128];   // 4 KB code tile
  __shared__ float S4[4][32];
  const int tid = threadIdx.x;
  const int lane = tid & 63;
  const int wave = tid >> 6;
  const int c = lane & 15;
  const int q = lane >> 4;
  const int qt = blockIdx.x;        // 0..31
  const int bh = blockIdx.y;        // 0..63
  const int b = bh >> 3;
  const int h = bh & 7;
  const size_t base = (size_t)bh << 16;
  const int ri = wave >> 1;         // output row-tile of this wave
  const int dh = wave & 1;          // output d-half of this wave

  // Q fragments (all 32 q rows), loaded once
  short8 aq[2][2];
#pragma unroll
  for (int qs = 0; qs < 2; qs++)
#pragma unroll
    for (int kk = 0; kk < 2; kk++)
      aq[qs][kk] = *(const short8*)(Qh + base + (size_t)(qt * 32 + qs * 16 + c) * 64 + kk * 32 + q * 8);

  const unsigned char* cbt = codes + ((size_t)b << 20) + ((size_t)(qt * 32 + (tid >> 3)) << 10) + (tid & 7) * 16;
  const unsigned short* Vb = Vt + base;

  float rs[2][4];
#pragma unroll
  for (int qs = 0; qs < 2; qs++)
#pragma unroll
    for (int r = 0; r < 4; r++) rs[qs][r] = 0.0f;
  floatx4 o[2];
  o[0] = (floatx4)(0.0f); o[1] = (floatx4)(0.0f);

  for (int kt = 0; kt < 8; kt++) {
    // stage code tile (coalesced 16B/lane)
    uint4 cw = *(const uint4*)(cbt + kt * 128);
    // S = Q K^T over this wave's 32-col stripe
    const int col0 = kt * 128 + wave * 32;
    floatx4 s[2][2];
#pragma unroll
    for (int qs = 0; qs < 2; qs++)
#pragma unroll
      for (int ci = 0; ci < 2; ci++) s[qs][ci] = (floatx4)(0.0f);
#pragma unroll
    for (int ci = 0; ci < 2; ci++)
#pragma unroll
      for (int kk = 0; kk < 2; kk++) {
        short8 bk = *(const short8*)(Kh + base + (size_t)(col0 + ci * 16 + c) * 64 + kk * 32 + q * 8);
        s[0][ci] = MFMA16(aq[0][kk], bk, s[0][ci]);
        s[1][ci] = MFMA16(aq[1][kk], bk, s[1][ci]);
      }
    *(uint4*)(&Ct[(tid >> 3) * 128 + (tid & 7) * 16]) = cw;
    __syncthreads();   // codes visible; prev PV reads of P complete

    // exp epilogue -> P tile + row-sum accumulation
#pragma unroll
    for (int qs = 0; qs < 2; qs++) {
      int rowb = qs * 16 + q * 4;
#pragma unroll
      for (int ci = 0; ci < 2; ci++) {
        int colw = wave * 32 + ci * 16 + c;
#pragma unroll
        for (int r = 0; r < 4; r++) {
          int row = rowb + r;
          unsigned char code = Ct[row * 128 + colw];
          // exp(s/8) = exp2(s * 0.125/ln2)
          float e = (h >= (int)code) ? exp2f(s[qs][ci][r] * 0.1803368801111362f) : 0.0f;
          rs[qs][r] += e;
          P[row * 136 + colw] = f2bf(e);
        }
      }
    }
    __syncthreads();   // P visible

    // PV: this wave's 16 rows x its 32 d-cols, k = this kt's 128 cols
#pragma unroll
    for (int ch = 0; ch < 4; ch++) {
      short8 ap = *(const short8*)(&P[(ri * 16 + c) * 136 + ch * 32 + q * 8]);
      short8 bv0 = *(const short8*)(Vb + (size_t)(dh * 32 + c) * 1024 + kt * 128 + ch * 32 + q * 8);
      short8 bv1 = *(const short8*)(Vb + (size_t)(dh * 32 + 16 + c) * 1024 + kt * 128 + ch * 32 + q * 8);
      o[0] = MFMA16(ap, bv0, o[0]);
      o[1] = MFMA16(ap, bv1, o[1]);
    }
  }

  // row sums: reduce over c lanes, then across waves via LDS
#pragma unroll
  for (int qs = 0; qs < 2; qs++)
#pragma unroll
    for (int r = 0; r < 4; r++) {
      float v = rs[qs][r];
      v += __shfl_xor(v, 1); v += __shfl_xor(v, 2);
      v += __shfl_xor(v, 4); v += __shfl_xor(v, 8);
      rs[qs][r] = v;
    }
  if (c == 0) {
#pragma unroll
    for (int qs = 0; qs < 2; qs++)
#pragma unroll
      for (int r = 0; r < 4; r++) S4[wave][qs * 16 + q * 4 + r] = rs[qs][r];
  }
  __syncthreads();
  float inv[4];
#pragma unroll
  for (int r = 0; r < 4; r++) {
    int row = ri * 16 + q * 4 + r;
    inv[r] = 1.0f / (S4[0][row] + S4[1][row] + S4[2][row] + S4[3][row]);
  }
  // write AO[b][n][h*64 + d]  (concat-heads layout for the output GEMM)
#pragma unroll
  for (int r = 0; r < 4; r++) {
    int ig = qt * 32 + ri * 16 + q * 4 + r;
    size_t ob = ((size_t)((b << 10) + ig)) * 512 + h * 64 + dh * 32;
    AO[ob + c] = f2bf(o[0][r] * inv[r]);
    AO[ob + 16 + c] = f2bf(o[1][r] * inv[r]);
  }
}

// ---------------- launcher ----------------
extern "C" void kernel_launch(void* const* d_in, const int* in_sizes, int n_in,
                              void* d_out, int out_size, void* d_ws, size_t ws_size,
                              hipStream_t stream) {
  const float* query = (const float*)d_in[0];
  const float* key_  = (const float*)d_in[1];
  const float* value = (const float*)d_in[2];
  const float* dist  = (const float*)d_in[3];
  const int*   mask  = (const int*)d_in[4];
  const float* Wq = (const float*)d_in[5];
  const float* bq = (const float*)d_in[6];
  const float* Wk = (const float*)d_in[7];
  const float* bk = (const float*)d_in[8];
  const float* Wv = (const float*)d_in[9];
  const float* bv = (const float*)d_in[10];
  const float* Wo = (const float*)d_in[11];
  const float* bo = (const float*)d_in[12];

  char* ws = (char*)d_ws;
  size_t off = 0;
  auto alloc = [&](size_t bytes) -> char* {
    char* p = ws + off;
    off += (bytes + 255) & ~(size_t)255;
    return p;
  };
  const size_t NQKV = 8192ull * 512;
  unsigned short* wq16 = (unsigned short*)alloc(512ull * 512 * 2);
  unsigned short* wk16 = (unsigned short*)alloc(512ull * 512 * 2);
  unsigned short* wv16 = (unsigned short*)alloc(512ull * 512 * 2);
  unsigned short* wo16 = (unsigned short*)alloc(512ull * 512 * 2);
  unsigned short* Qh = (unsigned short*)alloc(NQKV * 2);
  unsigned short* Kh = (unsigned short*)alloc(NQKV * 2);
  unsigned short* Vt = (unsigned short*)alloc(NQKV * 2);
  unsigned short* AO = (unsigned short*)alloc(NQKV * 2);
  unsigned char*  codes = (unsigned char*)alloc(8ull * 1024 * 1024);

  wcast_kernel<<<1024, 256, 0, stream>>>(Wq, Wk, Wv, Wo, wq16, wk16, wv16, wo16);
  codes_kernel<<<8192, 256, 0, stream>>>(dist, mask, codes);
  qkv_gemm<<<dim3(128, 4, 3), 256, 0, stream>>>(query, key_, value, wq16, wk16, wv16,
                                                bq, bk, bv, Qh, Kh, Vt);
  attn_kernel<<<dim3(32, 64), 256, 0, stream>>>(Qh, Kh, Vt, codes, AO);
  out_gemm<<<dim3(128, 4), 256, 0, stream>>>(AO, wo16, bo, (float*)d_out);
}

// Round 3
// 292.801 us; speedup vs baseline: 1.2244x; 1.0434x over previous
//
#include <hip/hip_runtime.h>
#include <stdint.h>

// ---------------------------------------------------------------------------
// MultiHeadedAttention: B=8, N=1024, E=512, H=8, D_K=64
// bf16 MFMA pipeline. Round 3: barrier-free flash attention — each wave owns
// 32 q-rows end-to-end; P transpose via wave-private LDS (lgkmcnt only).
// ---------------------------------------------------------------------------

typedef __attribute__((ext_vector_type(8))) short short8;
typedef __attribute__((ext_vector_type(4))) float floatx4;

#define MFMA16(a, b, c) __builtin_amdgcn_mfma_f32_16x16x32_bf16((a), (b), (c), 0, 0, 0)

static __device__ __forceinline__ unsigned short f2bf(float f) {
  union { float f; unsigned u; } v; v.f = f;
  unsigned r = v.u + 0x7fffu + ((v.u >> 16) & 1u);   // RNE
  return (unsigned short)(r >> 16);
}

// async global->LDS 16B/lane. LDS dest is wave-uniform base + lane*16 (m104).
static __device__ __forceinline__ void gload_lds16(const void* g, void* l) {
  __builtin_amdgcn_global_load_lds((const __attribute__((address_space(1))) unsigned int*)g,
                                   (__attribute__((address_space(3))) unsigned int*)l,
                                   16, 0, 0);
}
// chunk swizzle for unpadded 32-elem-wide bf16 LDS tiles (GEMM staging).
static __device__ __forceinline__ int xsw(int row) { return (row & 3) ^ ((row >> 2) & 3); }

// ---------------- weight cast fp32 -> bf16 (all 4 at once) ----------------
__global__ void wcast_kernel(const float* __restrict__ Wq, const float* __restrict__ Wk,
                             const float* __restrict__ Wv, const float* __restrict__ Wo,
                             unsigned short* __restrict__ o0, unsigned short* __restrict__ o1,
                             unsigned short* __restrict__ o2, unsigned short* __restrict__ o3) {
  int i = blockIdx.x * blockDim.x + threadIdx.x;   // 0..262143
  int w = i >> 16, loc = i & 65535;
  const float* s = (w == 0) ? Wq : (w == 1) ? Wk : (w == 2) ? Wv : Wo;
  unsigned short* d = (w == 0) ? o0 : (w == 1) ? o1 : (w == 2) ? o2 : o3;
  float4 v = ((const float4*)s)[loc];
  ushort4 o;
  o.x = f2bf(v.x); o.y = f2bf(v.y); o.z = f2bf(v.z); o.w = f2bf(v.w);
  ((ushort4*)d)[loc] = o;
}

// ---------------- dist+mask -> permuted code bytes ----------------
// allowed(h) <=> h >= code (DIST_BAR ascending). 0 on row/col 0; 9 if mask==0.
// Output layout matches the attn exp-epilogue exactly:
//   codesP[ (((b*32+rg)*8 + kt)*64 + lane)*64 + st*32 + ci*4 + r ]
// where row = rg*32 + st*16 + q*4 + r, col = kt*128 + ci*16 + c, lane = q*16+c.
// Each attn lane then reads its 64 bytes/kt as 4 coalesced dwordx4.
__global__ void codes_kernel(const float* __restrict__ dist, const int* __restrict__ mask,
                             unsigned char* __restrict__ codesP) {
  int t = blockIdx.x * blockDim.x + threadIdx.x;   // over B*N*N/4
  int flat = t << 2;
  int b = flat >> 20;
  int rem = flat & ((1 << 20) - 1);
  int row = rem >> 10;
  int col0 = rem & 1023;
  float4 d4 = ((const float4*)dist)[t];
  int4 m4 = ((const int4*)mask)[t];
  float dv[4] = {d4.x, d4.y, d4.z, d4.w};
  int mv[4] = {m4.x, m4.y, m4.z, m4.w};
  int rg = row >> 5;
  int st = (row >> 4) & 1;
  int qq = (row >> 2) & 3;
  int r = row & 3;
  size_t rowbase = (size_t)(b * 32 + rg) * 32768;   // *8 kt *4096
  int sub = st * 32 + r;
#pragma unroll
  for (int u = 0; u < 4; u++) {
    int col = col0 + u;
    float d = dv[u];
    int hmin = (d >= 0.2f) + (d >= 0.3f) + (d >= 0.4f) + (d >= 0.5f) +
               (d >= 0.6f) + (d >= 0.7f) + (d >= 0.8f) + (d >= 0.9f);
    unsigned char cc = (unsigned char)hmin;
    if (row == 0 || col == 0) cc = 0;
    if (mv[u] == 0) cc = 9;
    int kt = col >> 7, ci = (col >> 4) & 7, c = col & 15;
    int lane = qq * 16 + c;
    codesP[rowbase + (size_t)kt * 4096 + lane * 64 + sub + ci * 4] = cc;
  }
}

// ---------------- fused QKV projection GEMM ----------------
// C[m][n] = sum_k A[m][k] * W[n][k] + bias[n];  M=8192, N=512, K=512.
// 64x128 tile, 4 waves. A fp32 (cast fused). z=0/1: [bh][n][d]; z=2: [bh][d][n].
__global__ __launch_bounds__(256) void qkv_gemm(
    const float* __restrict__ Aq, const float* __restrict__ Ak, const float* __restrict__ Av,
    const unsigned short* __restrict__ Wqp, const unsigned short* __restrict__ Wkp,
    const unsigned short* __restrict__ Wvp,
    const float* __restrict__ bq, const float* __restrict__ bk, const float* __restrict__ bv,
    unsigned short* __restrict__ Qh, unsigned short* __restrict__ Kh,
    unsigned short* __restrict__ Vt) {
  const int z = blockIdx.z;
  const float* A = (z == 0) ? Aq : (z == 1) ? Ak : Av;
  const unsigned short* W = (z == 0) ? Wqp : (z == 1) ? Wkp : Wvp;
  const float* bias = (z == 0) ? bq : (z == 1) ? bk : bv;
  unsigned short* O = (z == 0) ? Qh : (z == 1) ? Kh : Vt;

  __shared__ __align__(16) short As[64 * 40];
  __shared__ __align__(16) short Bs[128 * 32];
  const int tid = threadIdx.x;
  const int lane = tid & 63;
  const int wave = tid >> 6;
  const int c = lane & 15;
  const int q = lane >> 4;
  const int m0 = blockIdx.x * 64;
  const int n0 = blockIdx.y * 128;
  const int wr = (wave >> 1) * 32;
  const int wc = (wave & 1) * 64;

  floatx4 acc[2][4];
#pragma unroll
  for (int i = 0; i < 2; i++)
#pragma unroll
    for (int j = 0; j < 4; j++) acc[i][j] = (floatx4)(0.0f);

  const int arow = tid >> 2, ach = tid & 3;
  const float* Ab = A + (size_t)(m0 + arow) * 512 + ach * 8;

  for (int k0 = 0; k0 < 512; k0 += 32) {
    __syncthreads();
#pragma unroll
    for (int it = 0; it < 2; it++) {
      int slot = wave * 128 + it * 64 + lane;
      int brow = slot >> 2, bch = slot & 3;
      int g = bch ^ xsw(brow);
      gload_lds16(W + (size_t)(n0 + brow) * 512 + k0 + g * 8,
                  &Bs[(size_t)(wave * 128 + it * 64) * 8]);
    }
    float4 a0 = *(const float4*)(Ab + k0);
    float4 a1 = *(const float4*)(Ab + k0 + 4);
    short8 av;
    av[0] = (short)f2bf(a0.x); av[1] = (short)f2bf(a0.y);
    av[2] = (short)f2bf(a0.z); av[3] = (short)f2bf(a0.w);
    av[4] = (short)f2bf(a1.x); av[5] = (short)f2bf(a1.y);
    av[6] = (short)f2bf(a1.z); av[7] = (short)f2bf(a1.w);
    *(short8*)(&As[arow * 40 + ach * 8]) = av;
    __syncthreads();

    short8 af[2], bfv[4];
#pragma unroll
    for (int i = 0; i < 2; i++)
      af[i] = *(const short8*)(&As[(wr + i * 16 + c) * 40 + q * 8]);
#pragma unroll
    for (int j = 0; j < 4; j++) {
      int row = wc + j * 16 + c;
      bfv[j] = *(const short8*)(&Bs[row * 32 + (q ^ xsw(row)) * 8]);
    }
#pragma unroll
    for (int i = 0; i < 2; i++)
#pragma unroll
      for (int j = 0; j < 4; j++)
        acc[i][j] = MFMA16(af[i], bfv[j], acc[i][j]);
  }

#pragma unroll
  for (int i = 0; i < 2; i++) {
    int gm0 = m0 + wr + i * 16 + q * 4;
#pragma unroll
    for (int j = 0; j < 4; j++) {
      int gn = n0 + wc + j * 16 + c;
      float bb = bias[gn];
      int h = gn >> 6, d = gn & 63;
      if (z == 2) {
        int b = gm0 >> 10, n = gm0 & 1023;
        ushort4 pk;
#pragma unroll
        for (int r = 0; r < 4; r++) pk[r] = f2bf(acc[i][j][r] + bb);
        *(ushort4*)(&Vt[(((size_t)(b * 8 + h) * 64 + d) << 10) + n]) = pk;  // [bh][d][n]
      } else {
#pragma unroll
        for (int r = 0; r < 4; r++) {
          int m = gm0 + r;
          int b = m >> 10, n = m & 1023;
          O[((((size_t)(b * 8 + h)) << 10) + n) * 64 + d] = f2bf(acc[i][j][r] + bb);
        }
      }
    }
  }
}

// ---------------- output projection GEMM (bf16 A, fp32 out) ----------------
__global__ __launch_bounds__(256) void out_gemm(const unsigned short* __restrict__ A,
                                                const unsigned short* __restrict__ W,
                                                const float* __restrict__ bias,
                                                float* __restrict__ Out) {
  __shared__ __align__(16) short As[64 * 32];
  __shared__ __align__(16) short Bs[128 * 32];
  const int tid = threadIdx.x;
  const int lane = tid & 63;
  const int wave = tid >> 6;
  const int c = lane & 15;
  const int q = lane >> 4;
  const int m0 = blockIdx.x * 64;
  const int n0 = blockIdx.y * 128;
  const int wr = (wave >> 1) * 32;
  const int wc = (wave & 1) * 64;

  floatx4 acc[2][4];
#pragma unroll
  for (int i = 0; i < 2; i++)
#pragma unroll
    for (int j = 0; j < 4; j++) acc[i][j] = (floatx4)(0.0f);

  for (int k0 = 0; k0 < 512; k0 += 32) {
    __syncthreads();
    {
      int slot = wave * 64 + lane;
      int arow = slot >> 2, ach = slot & 3;
      int g = ach ^ xsw(arow);
      gload_lds16(A + (size_t)(m0 + arow) * 512 + k0 + g * 8, &As[(size_t)(wave * 64) * 8]);
    }
#pragma unroll
    for (int it = 0; it < 2; it++) {
      int slot = wave * 128 + it * 64 + lane;
      int brow = slot >> 2, bch = slot & 3;
      int g = bch ^ xsw(brow);
      gload_lds16(W + (size_t)(n0 + brow) * 512 + k0 + g * 8,
                  &Bs[(size_t)(wave * 128 + it * 64) * 8]);
    }
    __syncthreads();

    short8 af[2], bfv[4];
#pragma unroll
    for (int i = 0; i < 2; i++) {
      int row = wr + i * 16 + c;
      af[i] = *(const short8*)(&As[row * 32 + (q ^ xsw(row)) * 8]);
    }
#pragma unroll
    for (int j = 0; j < 4; j++) {
      int row = wc + j * 16 + c;
      bfv[j] = *(const short8*)(&Bs[row * 32 + (q ^ xsw(row)) * 8]);
    }
#pragma unroll
    for (int i = 0; i < 2; i++)
#pragma unroll
      for (int j = 0; j < 4; j++)
        acc[i][j] = MFMA16(af[i], bfv[j], acc[i][j]);
  }

#pragma unroll
  for (int i = 0; i < 2; i++) {
    int gm0 = m0 + wr + i * 16 + q * 4;
#pragma unroll
    for (int j = 0; j < 4; j++) {
      int gn = n0 + wc + j * 16 + c;
      float bb = bias[gn];
#pragma unroll
      for (int r = 0; r < 4; r++)
        Out[(size_t)(gm0 + r) * 512 + gn] = acc[i][j][r] + bb;
    }
  }
}

// ---------------- barrier-free flash attention ----------------
// Wave w of WG (gx, bh) owns q-rows [gx*128 + w*32, +32) of head (b,h).
// Per 128-col K tile: S = QK^T (K frags from global) -> exp -> wave-private
// LDS P (C->A layout transform, lgkmcnt-ordered, NO barriers) -> PV.
// Row sums accumulate in registers; normalize in epilogue.
// P stride 132: write banks = (8q + 2r + 8ci + c/2) mod 32 — perfect spread.
__global__ __launch_bounds__(256) void attn_kernel(const unsigned short* __restrict__ Qh,
                                                   const unsigned short* __restrict__ Kh,
                                                   const unsigned short* __restrict__ Vt,
                                                   const unsigned char* __restrict__ codesP,
                                                   unsigned short* __restrict__ AO) {
  __shared__ __align__(16) unsigned short P[4][32 * 132];   // 33 KB, wave-private regions
  const int tid = threadIdx.x;
  const int lane = tid & 63;
  const int wave = tid >> 6;
  const int c = lane & 15;
  const int q = lane >> 4;
  const int bh = blockIdx.y;
  const int b = bh >> 3;
  const int h = bh & 7;
  const size_t base = (size_t)bh << 16;
  const int rbase = blockIdx.x * 128 + wave * 32;
  const int rg = rbase >> 5;
  unsigned short* Pw = &P[wave][0];

  // Q A-fragments for both 16-row stripes, held all kernel
  short8 aq[2][2];
#pragma unroll
  for (int st = 0; st < 2; st++)
#pragma unroll
    for (int kk = 0; kk < 2; kk++)
      aq[st][kk] = *(const short8*)(Qh + base + (size_t)(rbase + st * 16 + c) * 64 + kk * 32 + q * 8);

  const unsigned char* cbt = codesP + (size_t)(b * 32 + rg) * 32768 + lane * 64;
  const unsigned short* Kb = Kh + base;
  const unsigned short* Vb = Vt + base;

  float rs[2][4];
#pragma unroll
  for (int st = 0; st < 2; st++)
#pragma unroll
    for (int r = 0; r < 4; r++) rs[st][r] = 0.0f;
  floatx4 o[2][4];
#pragma unroll
  for (int st = 0; st < 2; st++)
#pragma unroll
    for (int ci = 0; ci < 4; ci++) o[st][ci] = (floatx4)(0.0f);

  for (int kt = 0; kt < 8; kt++) {
    // ---- QK^T: S[2 stripes][8 col-tiles], K frags straight from global ----
    const unsigned short* Kt = Kb + (size_t)kt * 128 * 64;
    floatx4 s[2][8];
#pragma unroll
    for (int ci = 0; ci < 8; ci++) { s[0][ci] = (floatx4)(0.0f); s[1][ci] = (floatx4)(0.0f); }
#pragma unroll
    for (int ci = 0; ci < 8; ci++)
#pragma unroll
      for (int kk = 0; kk < 2; kk++) {
        short8 bk = *(const short8*)(Kt + (size_t)(ci * 16 + c) * 64 + kk * 32 + q * 8);
        s[0][ci] = MFMA16(aq[0][kk], bk, s[0][ci]);
        s[1][ci] = MFMA16(aq[1][kk], bk, s[1][ci]);
      }
    // ---- codes: 64 bytes/lane, pre-permuted, 4 coalesced dwordx4 ----
    const unsigned char* cp = cbt + (size_t)kt * 4096;
    uint4 w0 = *(const uint4*)(cp);
    uint4 w1 = *(const uint4*)(cp + 16);
    uint4 w2 = *(const uint4*)(cp + 32);
    uint4 w3 = *(const uint4*)(cp + 48);
    unsigned cv[16] = {w0.x, w0.y, w0.z, w0.w, w1.x, w1.y, w1.z, w1.w,
                       w2.x, w2.y, w2.z, w2.w, w3.x, w3.y, w3.z, w3.w};
    // ---- exp epilogue -> wave-private P + register row sums ----
#pragma unroll
    for (int st = 0; st < 2; st++)
#pragma unroll
      for (int ci = 0; ci < 8; ci++)
#pragma unroll
        for (int r = 0; r < 4; r++) {
          int bidx = st * 32 + ci * 4 + r;                       // compile-time
          int code = (cv[bidx >> 2] >> ((bidx & 3) * 8)) & 0xff;
          float e = (h >= code) ? exp2f(s[st][ci][r] * 0.1803368801111362f) : 0.0f;
          rs[st][r] += e;
          Pw[(st * 16 + q * 4 + r) * 132 + ci * 16 + c] = f2bf(e);
        }
    // ---- PV: wave reads back its own P (lgkmcnt ordering, no barrier) ----
#pragma unroll
    for (int ch = 0; ch < 4; ch++) {
      short8 ap0 = *(const short8*)(&Pw[(size_t)c * 132 + ch * 32 + q * 8]);
      short8 ap1 = *(const short8*)(&Pw[(size_t)(16 + c) * 132 + ch * 32 + q * 8]);
#pragma unroll
      for (int ci = 0; ci < 4; ci++) {
        short8 bv = *(const short8*)(Vb + (size_t)(ci * 16 + c) * 1024 + kt * 128 + ch * 32 + q * 8);
        o[0][ci] = MFMA16(ap0, bv, o[0][ci]);
        o[1][ci] = MFMA16(ap1, bv, o[1][ci]);
      }
    }
  }

  // ---- normalize + write (all wave-local) ----
  float inv[2][4];
#pragma unroll
  for (int st = 0; st < 2; st++)
#pragma unroll
    for (int r = 0; r < 4; r++) {
      float v = rs[st][r];
      v += __shfl_xor(v, 1); v += __shfl_xor(v, 2);
      v += __shfl_xor(v, 4); v += __shfl_xor(v, 8);
      inv[st][r] = 1.0f / v;
    }
#pragma unroll
  for (int st = 0; st < 2; st++)
#pragma unroll
    for (int r = 0; r < 4; r++) {
      int n = rbase + st * 16 + q * 4 + r;
      size_t ob = ((size_t)((b << 10) + n)) * 512 + h * 64;
#pragma unroll
      for (int ci = 0; ci < 4; ci++)
        AO[ob + ci * 16 + c] = f2bf(o[st][ci][r] * inv[st][r]);
    }
}

// ---------------- launcher ----------------
extern "C" void kernel_launch(void* const* d_in, const int* in_sizes, int n_in,
                              void* d_out, int out_size, void* d_ws, size_t ws_size,
                              hipStream_t stream) {
  const float* query = (const float*)d_in[0];
  const float* key_  = (const float*)d_in[1];
  const float* value = (const float*)d_in[2];
  const float* dist  = (const float*)d_in[3];
  const int*   mask  = (const int*)d_in[4];
  const float* Wq = (const float*)d_in[5];
  const float* bq = (const float*)d_in[6];
  const float* Wk = (const float*)d_in[7];
  const float* bk = (const float*)d_in[8];
  const float* Wv = (const float*)d_in[9];
  const float* bv = (const float*)d_in[10];
  const float* Wo = (const float*)d_in[11];
  const float* bo = (const float*)d_in[12];

  char* ws = (char*)d_ws;
  size_t off = 0;
  auto alloc = [&](size_t bytes) -> char* {
    char* p = ws + off;
    off += (bytes + 255) & ~(size_t)255;
    return p;
  };
  const size_t NQKV = 8192ull * 512;
  unsigned short* wq16 = (unsigned short*)alloc(512ull * 512 * 2);
  unsigned short* wk16 = (unsigned short*)alloc(512ull * 512 * 2);
  unsigned short* wv16 = (unsigned short*)alloc(512ull * 512 * 2);
  unsigned short* wo16 = (unsigned short*)alloc(512ull * 512 * 2);
  unsigned short* Qh = (unsigned short*)alloc(NQKV * 2);
  unsigned short* Kh = (unsigned short*)alloc(NQKV * 2);
  unsigned short* Vt = (unsigned short*)alloc(NQKV * 2);
  unsigned short* AO = (unsigned short*)alloc(NQKV * 2);
  unsigned char*  codesP = (unsigned char*)alloc(8ull * 1024 * 1024);

  wcast_kernel<<<1024, 256, 0, stream>>>(Wq, Wk, Wv, Wo, wq16, wk16, wv16, wo16);
  codes_kernel<<<8192, 256, 0, stream>>>(dist, mask, codesP);
  qkv_gemm<<<dim3(128, 4, 3), 256, 0, stream>>>(query, key_, value, wq16, wk16, wv16,
                                                bq, bk, bv, Qh, Kh, Vt);
  attn_kernel<<<dim3(8, 64), 256, 0, stream>>>(Qh, Kh, Vt, codesP, AO);
  out_gemm<<<dim3(128, 4), 256, 0, stream>>>(AO, wo16, bo, (float*)d_out);
}